// Round 5
// baseline (108.264 us; speedup 1.0000x reference)
//
#include <hip/hip_runtime.h>

// Problem constants (reference: shape (2,1,160,192,160), win=9)
#define BB 2
#define DD 160
#define HH 192
#define WW 160
#define HW (HH * WW)
#define PAD 4
#define TH 16
#define TW 16
#define EXT 24              // TH+2*PAD == TW+2*PAD
#define XSTR 28             // plane row stride (words, 16B-aligned rows)
#define PLW 672             // plane words = EXT*XSTR
// LDS layout (words) in one packed array L[9984] = 39936 B -> 4 blocks/CU
#define ONESB 2688          // 32 words of 1.0f
#define WSB 2720            // wsum: 2 slices x 5ch x WCS
#define WSS 2260            // wsum slice stride (5*WCS)
#define WCS 452             // wsum channel stride (>=16*28+24; ==4 mod 32)
#define WJS 28              // wsum col(j) stride (r contiguous)
#define HSB 7240            // hsum: 2 slices x 5ch x HCS
#define HSS 1365            // hsum slice stride (5*HCS)
#define HCS 273             // hsum channel stride (odd)
#define HHS 17              // hsum row stride
#define REDB 9972
#define LWORDS 9984
#define CHUNK 28
#define NCH 6               // ceil(DD/CHUNK)
#define NPAIR 18            // (CHUNK+8)/2
#define WT (WW / TW)        // 10
#define HT (HH / TH)        // 12
#define NBLK (WT * HT * NCH * BB)  // 1440
#define EPS 1e-5f
#define INV_WS (1.0f / 729.0f)

// barrier that waits LDS only — never drains vmcnt (keeps prefetch in flight)
__device__ __forceinline__ void bar_lgkm() {
  asm volatile("s_waitcnt lgkmcnt(0)" ::: "memory");
  __builtin_amdgcn_s_barrier();
  asm volatile("" ::: "memory");
}

__global__ void __launch_bounds__(256, 4) k_lncc(
    const float* __restrict__ x, const float* __restrict__ y,
    float* __restrict__ partials)
{
  __shared__ float L[LWORDS];

  const int t = threadIdx.x;
  const int w0 = blockIdx.x * TW;
  const int h0 = blockIdx.y * TH;
  const int bz = blockIdx.z;
  const int b = bz / NCH;
  const int chunk = bz - b * NCH;
  const int dc0 = chunk * CHUNK;
  const int g0 = dc0 - PAD;

  // ---- init: zero planes (OOB slots stay 0 forever), ones row ----
  for (int i = t; i < WSB; i += 256) L[i] = (i >= ONESB) ? 1.0f : 0.0f;
  __syncthreads();

  // ---- staging task descriptors: 576 float4-groups over 256 threads ----
  // tau = t + 256k; tau -> (slice s, array a, row r, group q)
  int laddr0, laddr1, laddr2;
  int tslc0, tslc1, tslc2;
  bool tok0, tok1, tok2;
  const float* gp0; const float* gp1; const float* gp2;
  {
    const float* bx = x + (long)b * DD * HW;
    const float* by = y + (long)b * DD * HW;
#define MKTASK(K, LA, TS, TK, GP)                                         \
    {                                                                     \
      int tau = t + 256 * K;                                              \
      int s = tau / 288;                                                  \
      int rem = tau - 288 * s;                                            \
      int a = rem / 144;                                                  \
      int rho = rem - 144 * a;                                            \
      int r = rho / 6;                                                    \
      int q = rho - 6 * r;                                                \
      int gh = h0 - PAD + r;                                              \
      int gw = w0 - PAD + 4 * q;                                          \
      bool ok = (tau < 576) && ((unsigned)gh < (unsigned)HH) &&           \
                ((unsigned)gw < (unsigned)WW);                            \
      LA = ok ? ((2 * s + a) * PLW + r * XSTR + 4 * q) : 0;               \
      TS = (s < 2) ? s : 0;                                               \
      TK = ok;                                                            \
      GP = (a ? by : bx) + (long)TS * HW + (ok ? (gh * WW + gw) : 0);     \
    }
    MKTASK(0, laddr0, tslc0, tok0, gp0)
    MKTASK(1, laddr1, tslc1, tok1, gp1)
    MKTASK(2, laddr2, tslc2, tok2, gp2)
#undef MKTASK
  }

  // ---- P2 constants (t<240): r-major -> same-row lanes broadcast ----
  const int s2 = (t >= 120) ? 1 : 0;
  const int t2 = t - 120 * s2;
  const int r2 = t2 / 5;
  const int c2 = t2 - 5 * r2;
  const int paOff = (2 * s2 + (((c2 == 1) || (c2 == 3)) ? 1 : 0)) * PLW + r2 * XSTR;
  const int pbOff = (c2 < 2) ? ONESB
                             : ((2 * s2 + ((c2 == 2) ? 0 : 1)) * PLW + r2 * XSTR);
  const int wwOff = WSB + s2 * WSS + c2 * WCS + r2;

  // ---- P3 constants (t<160): w-major ----
  const int s3 = (t >= 80) ? 1 : 0;
  const int t3 = t - 80 * s3;
  const int w3 = t3 / 5;
  const int c3 = t3 - 5 * w3;
  const int rdOff = WSB + s3 * WSS + c3 * WCS + w3 * WJS;
  const int hwOff = HSB + s3 * HSS + c3 * HCS + w3;

  // ---- P4 constants ----
  const int h4 = t >> 4, w4 = t & 15;
  const int hrd = HSB + h4 * HHS + w4;

  // ---- D-window ring (static idx), running sums ----
  float ring[9][5];
#pragma unroll
  for (int i = 0; i < 9; ++i)
#pragma unroll
    for (int c = 0; c < 5; ++c) ring[i][c] = 0.f;
  float run0 = 0.f, run1 = 0.f, run2 = 0.f, run3 = 0.f, run4 = 0.f, acc = 0.f;

  // ---- prologue: prefetch pair 0 ----
  float4 stg0 = make_float4(0, 0, 0, 0), stg1 = stg0, stg2 = stg0;
  bool pst0, pst1, pst2;
  {
    const bool v0 = ((unsigned)g0 < (unsigned)DD);
    const bool v1 = ((unsigned)(g0 + 1) < (unsigned)DD);
    const long off64 = (long)g0 * HW;
    pst0 = tok0 && (tslc0 ? v1 : v0);
    if (pst0) stg0 = *(const float4*)(gp0 + off64);
    pst1 = tok1 && (tslc1 ? v1 : v0);
    if (pst1) stg1 = *(const float4*)(gp1 + off64);
    pst2 = tok2 && (tslc2 ? v1 : v0);
    if (pst2) stg2 = *(const float4*)(gp2 + off64);
  }

  for (int o = 0; o < 2; ++o) {
#pragma unroll
    for (int j = 0; j < 9; ++j) {
      const int kit = o * 9 + j;
      const int gs0 = g0 + 2 * kit;
      const bool gv0 = ((unsigned)gs0 < (unsigned)DD);
      const bool gv1 = ((unsigned)(gs0 + 1) < (unsigned)DD);

      // store staged pair -> planes (b128; OOB lanes simply don't store)
      if (pst0) *(float4*)&L[laddr0] = stg0;
      if (pst1) *(float4*)&L[laddr1] = stg1;
      if (pst2) *(float4*)&L[laddr2] = stg2;

      // prefetch next pair (stays in flight across all barriers)
      {
        const int gn = gs0 + 2;
        const bool nv0 = ((unsigned)gn < (unsigned)DD) && (kit + 1 < NPAIR);
        const bool nv1 = ((unsigned)(gn + 1) < (unsigned)DD) && (kit + 1 < NPAIR);
        const long off64 = (long)gn * HW;
        pst0 = tok0 && (tslc0 ? nv1 : nv0);
        if (pst0) stg0 = *(const float4*)(gp0 + off64);
        pst1 = tok1 && (tslc1 ? nv1 : nv0);
        if (pst1) stg1 = *(const float4*)(gp1 + off64);
        pst2 = tok2 && (tslc2 ? nv1 : nv0);
        if (pst2) stg2 = *(const float4*)(gp2 + off64);
      }

      float h00 = 0.f, h01 = 0.f, h02 = 0.f, h03 = 0.f, h04 = 0.f;
      float h10 = 0.f, h11 = 0.f, h12 = 0.f, h13 = 0.f, h14 = 0.f;

      if (gv0 || gv1) {            // block-uniform
        bar_lgkm();  // A: planes visible
        // ---- P2: sliding W-filter, 240 tasks (2 slices x 5ch x 24 rows) ----
        if (t < 240) {
          const bool gvs = s2 ? gv1 : gv0;
          if (gvs) {
            const float* pa = &L[paOff];
            const float* pb = &L[pbOff];
            float qv[EXT];
#pragma unroll
            for (int i = 0; i < EXT; ++i) qv[i] = pa[i] * pb[i];
            float s = ((qv[0] + qv[1]) + (qv[2] + qv[3])) +
                      ((qv[4] + qv[5]) + (qv[6] + qv[7])) + qv[8];
            L[wwOff] = s;
#pragma unroll
            for (int jj = 1; jj < TW; ++jj) {
              s += qv[jj + 8] - qv[jj - 1];
              L[wwOff + jj * WJS] = s;
            }
          }
        }
        bar_lgkm();  // B
        // ---- P3: sliding H-filter, 160 tasks (2 x 5 x 16 cols) ----
        if (t < 160) {
          const bool gvs = s3 ? gv1 : gv0;
          if (gvs) {
            const float* v = &L[rdOff];
            float vv[EXT];
#pragma unroll
            for (int i = 0; i < EXT; ++i) vv[i] = v[i];
            float s = ((vv[0] + vv[1]) + (vv[2] + vv[3])) +
                      ((vv[4] + vv[5]) + (vv[6] + vv[7])) + vv[8];
            L[hwOff] = s;
#pragma unroll
            for (int hh = 1; hh < TH; ++hh) {
              s += vv[hh + 8] - vv[hh - 1];
              L[hwOff + hh * HHS] = s;
            }
          }
        }
        bar_lgkm();  // C
        if (gv0) {
          h00 = L[hrd];           h01 = L[hrd + HCS];     h02 = L[hrd + 2 * HCS];
          h03 = L[hrd + 3 * HCS]; h04 = L[hrd + 4 * HCS];
        }
        if (gv1) {
          h10 = L[hrd + HSS];           h11 = L[hrd + HSS + HCS];
          h12 = L[hrd + HSS + 2 * HCS]; h13 = L[hrd + HSS + 3 * HCS];
          h14 = L[hrd + HSS + 4 * HCS];
        }
      }

      // ---- D running sums; static ring indices ((2j)%9 folds) ----
      {
        const int ra = (2 * j) % 9;
        run0 += h00 - ring[ra][0]; ring[ra][0] = h00;
        run1 += h01 - ring[ra][1]; ring[ra][1] = h01;
        run2 += h02 - ring[ra][2]; ring[ra][2] = h02;
        run3 += h03 - ring[ra][3]; ring[ra][3] = h03;
        run4 += h04 - ring[ra][4]; ring[ra][4] = h04;
        const int d0v = gs0 - PAD;
        if (d0v >= dc0 && d0v < DD) {
          float cross = fmaf(-run0 * INV_WS, run1, run4);
          float xv = fmaxf(fmaf(-run0 * INV_WS, run0, run2), EPS);
          float yv = fmaxf(fmaf(-run1 * INV_WS, run1, run3), EPS);
          acc += (cross * cross) * __builtin_amdgcn_rcpf(xv * yv);
        }
      }
      {
        const int rb = (2 * j + 1) % 9;
        run0 += h10 - ring[rb][0]; ring[rb][0] = h10;
        run1 += h11 - ring[rb][1]; ring[rb][1] = h11;
        run2 += h12 - ring[rb][2]; ring[rb][2] = h12;
        run3 += h13 - ring[rb][3]; ring[rb][3] = h13;
        run4 += h14 - ring[rb][4]; ring[rb][4] = h14;
        const int d1v = gs0 + 1 - PAD;
        if (d1v >= dc0 && d1v < DD) {
          float cross = fmaf(-run0 * INV_WS, run1, run4);
          float xv = fmaxf(fmaf(-run0 * INV_WS, run0, run2), EPS);
          float yv = fmaxf(fmaf(-run1 * INV_WS, run1, run3), EPS);
          acc += (cross * cross) * __builtin_amdgcn_rcpf(xv * yv);
        }
      }
    }
  }

  // ---- block reduction ----
#pragma unroll
  for (int off2 = 32; off2 > 0; off2 >>= 1) acc += __shfl_down(acc, off2);
  if ((t & 63) == 0) L[REDB + (t >> 6)] = acc;
  __syncthreads();
  if (t == 0) {
    int bid = (bz * HT + blockIdx.y) * WT + blockIdx.x;
    partials[bid] = (L[REDB] + L[REDB + 1]) + (L[REDB + 2] + L[REDB + 3]);
  }
}

__global__ void __launch_bounds__(256) k_finalize(
    const float* __restrict__ partials, float* __restrict__ out)
{
  __shared__ double red[256];
  double s = 0.0;
  for (int i = threadIdx.x; i < NBLK; i += 256) s += (double)partials[i];
  red[threadIdx.x] = s;
  __syncthreads();
  for (int o = 128; o > 0; o >>= 1) {
    if (threadIdx.x < o) red[threadIdx.x] += red[threadIdx.x + o];
    __syncthreads();
  }
  if (threadIdx.x == 0) {
    const double Nvox = (double)BB * DD * HH * WW;
    out[0] = (float)(-red[0] / Nvox);
  }
}

extern "C" void kernel_launch(void* const* d_in, const int* in_sizes, int n_in,
                              void* d_out, int out_size, void* d_ws, size_t ws_size,
                              hipStream_t stream) {
  (void)in_sizes; (void)n_in; (void)out_size; (void)ws_size;
  const float* x = (const float*)d_in[0];
  const float* y = (const float*)d_in[1];
  float* out = (float*)d_out;
  float* partials = (float*)d_ws;

  dim3 grid(WT, HT, BB * NCH);
  k_lncc<<<grid, 256, 0, stream>>>(x, y, partials);
  k_finalize<<<1, 256, 0, stream>>>(partials, out);
}

// Round 6
// 79.984 us; speedup vs baseline: 1.3536x; 1.3536x over previous
//
#include <hip/hip_runtime.h>

// Problem constants (reference: shape (2,1,160,192,160), win=9)
#define BB 2
#define DD 160
#define HH 192
#define WW 160
#define HW (HH * WW)
#define PAD 4
#define TH 16
#define TW 16
#define EXT 24              // TH+2*PAD == TW+2*PAD
#define XSTR 28             // plane row stride (words; rows 16B-aligned)
#define PLANE 768           // words per (parity,arr) plane (>= EXT*XSTR=672)
#define WCS 456             // wsum channel stride (>= 15*28+23; ==8 mod 32)
#define WJS 28              // wsum j(col) stride (r contiguous, 16B-aligned)
#define HCS 272             // hsum channel stride
#define HHS 17              // hsum row stride (odd -> staggered)
#define CHUNK 28
#define NCH 6               // ceil(DD/CHUNK)
#define NITER 36            // CHUNK + 2*PAD = 4*9 (static ring indexing)
#define WT (WW / TW)        // 10
#define HT (HH / TH)        // 12
#define NBLK (WT * HT * NCH * BB)  // 1440
#define NTASK 288           // staging float4 tasks per slice (2 arr x 24 r x 6 q)
#define EPS 1e-5f
#define INV_WS (1.0f / 729.0f)

// barrier that waits LDS only — never drains vmcnt (keeps prefetch in flight)
__device__ __forceinline__ void bar_lgkm() {
  asm volatile("s_waitcnt lgkmcnt(0)" ::: "memory");
  __builtin_amdgcn_s_barrier();
  asm volatile("" ::: "memory");
}

__global__ void __launch_bounds__(256) k_lncc(
    const float* __restrict__ x, const float* __restrict__ y,
    float* __restrict__ partials)
{
  __shared__ __align__(16) float sbuf[2][2][PLANE];  // [parity][arr] 12288 B
  __shared__ __align__(16) float ones[32];
  __shared__ __align__(16) float wsum[5 * WCS];      // 9120 B  [c][j][r]
  __shared__ __align__(16) float hsum[5 * HCS];      // 5440 B  [c][h*HHS+w]
  __shared__ float red[4];

  const int t = threadIdx.x;
  const int w0 = blockIdx.x * TW;
  const int h0 = blockIdx.y * TH;
  const int bz = blockIdx.z;
  const int b = bz / NCH;
  const int chunk = bz - b * NCH;
  const int dc0 = chunk * CHUNK;
  const int g0 = dc0 - PAD;

  // ---- init: zero both parity planes (OOB slots stay 0 forever); ones ----
  for (int i = t; i < 2 * 2 * PLANE; i += 256) (&sbuf[0][0][0])[i] = 0.f;
  if (t < 32) ones[t] = 1.0f;
  __syncthreads();

  // ---- staging descriptors: NTASK float4 tasks; thread t gets t and 256+t ----
  int la0, la1; bool tk0, tk1;
  const float* gp0; const float* gp1;
  {
    const float* bx = x + (long)b * DD * HW;
    const float* by = y + (long)b * DD * HW;
#define MKTASK(TAU, LA, TK, GP)                                           \
    {                                                                     \
      int tau = (TAU);                                                    \
      int a = tau / 144;                                                  \
      int rem = tau - 144 * a;                                            \
      int r = rem / 6;                                                    \
      int q = rem - 6 * r;                                                \
      int aa = (a < 2) ? a : 0;                                           \
      int gh = h0 - PAD + r;                                              \
      int gw = w0 - PAD + 4 * q;                                          \
      bool ok = (tau < NTASK) && ((unsigned)gh < (unsigned)HH) &&         \
                ((unsigned)gw < (unsigned)WW);                            \
      LA = aa * PLANE + r * XSTR + 4 * q;                                 \
      TK = ok;                                                            \
      GP = (aa ? by : bx) + (ok ? (gh * WW + gw) : 0);                    \
    }
    MKTASK(t, la0, tk0, gp0)
    MKTASK(256 + t, la1, tk1, gp1)
#undef MKTASK
  }

  // ---- P2 constants (t<120): task = (channel c2, ext row r2) ----
  const int c2 = t / 24, r2 = t - c2 * 24;
  const int arrA = ((c2 == 1) || (c2 == 3)) ? 1 : 0;
  const int arrB = (c2 == 2) ? 0 : 1;
  const bool useOnes = (c2 < 2);
  const int paOff = arrA * PLANE + r2 * XSTR;   // + p*2*PLANE
  const int pbOff = arrB * PLANE + r2 * XSTR;   // + p*2*PLANE (if !useOnes)
  float* const wwr = &wsum[c2 * WCS + r2];      // + j*WJS

  // ---- P3 constants (t<80): task = (channel c3, out col w3) ----
  const int c3 = t / 16, w3 = t - c3 * 16;
  const float* const wrd = &wsum[c3 * WCS + w3 * WJS];  // + i contiguous
  float* const hwr = &hsum[c3 * HCS + w3];              // + h*HHS

  // ---- P4 constants: one output (h,w) per thread ----
  const int h4 = t >> 4, w4 = t & 15;
  const float* const hrd = &hsum[h4 * HHS + w4];        // + c*HCS

  // ---- D-window ring (static idx), running sums ----
  float ring[9][5];
#pragma unroll
  for (int i = 0; i < 9; ++i)
#pragma unroll
    for (int c = 0; c < 5; ++c) ring[i][c] = 0.f;
  float run0 = 0.f, run1 = 0.f, run2 = 0.f, run3 = 0.f, run4 = 0.f, acc = 0.f;

  // ---- prologue: prefetch slice g0 into regs ----
  float4 st0 = make_float4(0, 0, 0, 0), st1 = st0;
  bool ps0 = false, ps1 = false;
  if (g0 >= 0) {
    const long so = (long)g0 * HW;
    ps0 = tk0; if (ps0) st0 = *(const float4*)(gp0 + so);
    ps1 = tk1; if (ps1) st1 = *(const float4*)(gp1 + so);
  }

  for (int ito = 0; ito < NITER; ito += 9) {
#pragma unroll
    for (int jj = 0; jj < 9; ++jj) {
      const int it = ito + jj;
      const int g = g0 + it;
      const int p = it & 1;
      const bool gv = ((unsigned)g < (unsigned)DD);  // block-uniform
      float hv0 = 0.f, hv1 = 0.f, hv2 = 0.f, hv3 = 0.f, hv4 = 0.f;

      // store staged regs (slice g) -> planes[p]; OOB lanes skip (pre-zeroed)
      {
        float* lb = &sbuf[p][0][0];
        if (ps0) *(float4*)(lb + la0) = st0;
        if (ps1) *(float4*)(lb + la1) = st1;
      }
      // prefetch next slice (stays in flight across all barriers)
      {
        const int gn = g + 1;
        const bool nv = ((unsigned)gn < (unsigned)DD) && (it + 1 < NITER);
        const long so = (long)gn * HW;
        ps0 = tk0 && nv; if (ps0) st0 = *(const float4*)(gp0 + so);
        ps1 = tk1 && nv; if (ps1) st1 = *(const float4*)(gp1 + so);
      }

      if (gv) {
        bar_lgkm();  // A: planes[p] visible
        // ---- P2: sliding W-filter (b128 row reads) ----
        if (t < 120) {
          const int pb2 = p * 2 * PLANE;
          const float* pa = &sbuf[0][0][0] + pb2 + paOff;
          const float* pb = useOnes ? &ones[0] : (&sbuf[0][0][0] + pb2 + pbOff);
          float4 A0 = *(const float4*)(pa);
          float4 A1 = *(const float4*)(pa + 4);
          float4 A2 = *(const float4*)(pa + 8);
          float4 A3 = *(const float4*)(pa + 12);
          float4 A4 = *(const float4*)(pa + 16);
          float4 A5 = *(const float4*)(pa + 20);
          float4 B0 = *(const float4*)(pb);
          float4 B1 = *(const float4*)(pb + (useOnes ? 0 : 4));
          float4 B2 = *(const float4*)(pb + (useOnes ? 0 : 8));
          float4 B3 = *(const float4*)(pb + (useOnes ? 0 : 12));
          float4 B4 = *(const float4*)(pb + (useOnes ? 0 : 16));
          float4 B5 = *(const float4*)(pb + (useOnes ? 0 : 20));
          float q[EXT];
          q[0]=A0.x*B0.x; q[1]=A0.y*B0.y; q[2]=A0.z*B0.z; q[3]=A0.w*B0.w;
          q[4]=A1.x*B1.x; q[5]=A1.y*B1.y; q[6]=A1.z*B1.z; q[7]=A1.w*B1.w;
          q[8]=A2.x*B2.x; q[9]=A2.y*B2.y; q[10]=A2.z*B2.z; q[11]=A2.w*B2.w;
          q[12]=A3.x*B3.x; q[13]=A3.y*B3.y; q[14]=A3.z*B3.z; q[15]=A3.w*B3.w;
          q[16]=A4.x*B4.x; q[17]=A4.y*B4.y; q[18]=A4.z*B4.z; q[19]=A4.w*B4.w;
          q[20]=A5.x*B5.x; q[21]=A5.y*B5.y; q[22]=A5.z*B5.z; q[23]=A5.w*B5.w;
          float s = ((q[0] + q[1]) + (q[2] + q[3])) +
                    ((q[4] + q[5]) + (q[6] + q[7])) + q[8];
          wwr[0] = s;
#pragma unroll
          for (int j = 1; j < TW; ++j) {
            s += q[j + 8] - q[j - 1];
            wwr[j * WJS] = s;
          }
        }
        bar_lgkm();  // B
        // ---- P3: sliding H-filter (b128 contiguous reads) ----
        if (t < 80) {
          float4 V0 = *(const float4*)(wrd);
          float4 V1 = *(const float4*)(wrd + 4);
          float4 V2 = *(const float4*)(wrd + 8);
          float4 V3 = *(const float4*)(wrd + 12);
          float4 V4 = *(const float4*)(wrd + 16);
          float4 V5 = *(const float4*)(wrd + 20);
          float v[EXT];
          v[0]=V0.x; v[1]=V0.y; v[2]=V0.z; v[3]=V0.w;
          v[4]=V1.x; v[5]=V1.y; v[6]=V1.z; v[7]=V1.w;
          v[8]=V2.x; v[9]=V2.y; v[10]=V2.z; v[11]=V2.w;
          v[12]=V3.x; v[13]=V3.y; v[14]=V3.z; v[15]=V3.w;
          v[16]=V4.x; v[17]=V4.y; v[18]=V4.z; v[19]=V4.w;
          v[20]=V5.x; v[21]=V5.y; v[22]=V5.z; v[23]=V5.w;
          float s = ((v[0] + v[1]) + (v[2] + v[3])) +
                    ((v[4] + v[5]) + (v[6] + v[7])) + v[8];
          hwr[0] = s;
#pragma unroll
          for (int h = 1; h < TH; ++h) {
            s += v[h + 8] - v[h - 1];
            hwr[h * HHS] = s;
          }
        }
        bar_lgkm();  // C
        hv0 = hrd[0];
        hv1 = hrd[HCS];
        hv2 = hrd[2 * HCS];
        hv3 = hrd[3 * HCS];
        hv4 = hrd[4 * HCS];
      }

      // ---- D running sums; ring[jj] static -> no register shifting ----
      run0 += hv0 - ring[jj][0]; ring[jj][0] = hv0;
      run1 += hv1 - ring[jj][1]; ring[jj][1] = hv1;
      run2 += hv2 - ring[jj][2]; ring[jj][2] = hv2;
      run3 += hv3 - ring[jj][3]; ring[jj][3] = hv3;
      run4 += hv4 - ring[jj][4]; ring[jj][4] = hv4;

      if (it >= 8) {
        const int d = g - PAD;          // = dc0 + it - 8
        if (d < DD) {                   // block-uniform tail guard
          float cross = fmaf(-run0 * INV_WS, run1, run4);
          float xv = fmaxf(fmaf(-run0 * INV_WS, run0, run2), EPS);
          float yv = fmaxf(fmaf(-run1 * INV_WS, run1, run3), EPS);
          acc += (cross * cross) * __builtin_amdgcn_rcpf(xv * yv);
        }
      }
    }
  }

  // ---- block reduction ----
#pragma unroll
  for (int o = 32; o > 0; o >>= 1) acc += __shfl_down(acc, o);
  if ((t & 63) == 0) red[t >> 6] = acc;
  __syncthreads();
  if (t == 0) {
    int bid = (bz * HT + blockIdx.y) * WT + blockIdx.x;
    partials[bid] = (red[0] + red[1]) + (red[2] + red[3]);
  }
}

__global__ void __launch_bounds__(256) k_finalize(
    const float* __restrict__ partials, float* __restrict__ out)
{
  __shared__ double red[256];
  double s = 0.0;
  for (int i = threadIdx.x; i < NBLK; i += 256) s += (double)partials[i];
  red[threadIdx.x] = s;
  __syncthreads();
  for (int o = 128; o > 0; o >>= 1) {
    if (threadIdx.x < o) red[threadIdx.x] += red[threadIdx.x + o];
    __syncthreads();
  }
  if (threadIdx.x == 0) {
    const double Nvox = (double)BB * DD * HH * WW;
    out[0] = (float)(-red[0] / Nvox);
  }
}

extern "C" void kernel_launch(void* const* d_in, const int* in_sizes, int n_in,
                              void* d_out, int out_size, void* d_ws, size_t ws_size,
                              hipStream_t stream) {
  (void)in_sizes; (void)n_in; (void)out_size; (void)ws_size;
  const float* x = (const float*)d_in[0];
  const float* y = (const float*)d_in[1];
  float* out = (float*)d_out;
  float* partials = (float*)d_ws;

  dim3 grid(WT, HT, BB * NCH);
  k_lncc<<<grid, 256, 0, stream>>>(x, y, partials);
  k_finalize<<<1, 256, 0, stream>>>(partials, out);
}